// Round 15
// baseline (210.718 us; speedup 1.0000x reference)
//
#include <hip/hip_runtime.h>
#include <cstddef>

#define BSZ   1024
#define TT    128
#define LAB   64
#define DEMO  16
#define HID   32
#define FF    4

// sigmoid(pre) with pre' = -log2(e)*pre folded into weights: rcp(1+exp2(pre'))
// tanh(y) with y' = 2*log2(e)*y folded into weights: 1 - 2*rcp(exp2(y')+1)
__device__ __forceinline__ float sig_s(float p) {
    return __builtin_amdgcn_rcpf(1.0f + __builtin_amdgcn_exp2f(p));
}
__device__ __forceinline__ float tanh_s(float y) {
    return fmaf(-2.0f, __builtin_amdgcn_rcpf(__builtin_amdgcn_exp2f(y) + 1.0f), 1.0f);
}

// DPP quad_perm (full-rate VALU cross-lane within aligned 4-lane groups; no LDS pipe)
template<int CTRL>
__device__ __forceinline__ float dpp_f(float v) {
    return __int_as_float(__builtin_amdgcn_mov_dpp(__float_as_int(v), CTRL, 0xf, 0xf, true));
}
#define QP_XOR1 0xB1  // [1,0,3,2]
#define QP_XOR2 0x4E  // [2,3,0,1]
#define QP_BC0  0x00  // all lanes <- quad lane 0
#define QP_BC1  0x55
#define QP_BC2  0xAA
#define QP_BC3  0xFF

// One GRU step for this lane's (lab, f): X0..X3 = 16 consecutive x floats (f-slice)
#define GRU_STEP(X0, X1, X2, X3) do {                                            \
    float a0 = fmaf((X3).x, wl3.x, fmaf((X2).x, wl2.x, fmaf((X1).x, wl1.x, (X0).x * wl0.x))); \
    float a1 = fmaf((X3).y, wl3.y, fmaf((X2).y, wl2.y, fmaf((X1).y, wl1.y, (X0).y * wl0.y))); \
    float a2 = fmaf((X3).z, wl3.z, fmaf((X2).z, wl2.z, fmaf((X1).z, wl1.z, (X0).z * wl0.z))); \
    float a3 = fmaf((X3).w, wl3.w, fmaf((X2).w, wl2.w, fmaf((X1).w, wl1.w, (X0).w * wl0.w))); \
    float p = (a0 + a1) + (a2 + a3);                                             \
    p += dpp_f<QP_XOR1>(p);                                                      \
    p += dpp_f<QP_XOR2>(p);            /* all 4 lanes now hold the full dot */   \
    const float xt = p + lb;                                                     \
    const float hh0 = dpp_f<QP_BC0>(h);                                          \
    const float hh1 = dpp_f<QP_BC1>(h);                                          \
    const float hh2 = dpp_f<QP_BC2>(h);                                          \
    const float hh3 = dpp_f<QP_BC3>(h);                                          \
    float pr = fmaf(xt, wir, bcr);                                               \
    pr = fmaf(hh0, whr.x, pr); pr = fmaf(hh1, whr.y, pr);                        \
    pr = fmaf(hh2, whr.z, pr); pr = fmaf(hh3, whr.w, pr);                        \
    float pz = fmaf(xt, wiz, bcz);                                               \
    pz = fmaf(hh0, whz.x, pz); pz = fmaf(hh1, whz.y, pz);                        \
    pz = fmaf(hh2, whz.z, pz); pz = fmaf(hh3, whz.w, pz);                        \
    const float r = sig_s(pr);                                                   \
    const float z = sig_s(pz);                                                   \
    float gh = fmaf(hh0, whn.x, bhn); gh = fmaf(hh1, whn.y, gh);                 \
    gh = fmaf(hh2, whn.z, gh); gh = fmaf(hh3, whn.w, gh);                        \
    const float gi = fmaf(xt, win, bin);                                         \
    const float nn = tanh_s(fmaf(r, gh, gi));                                    \
    h = fmaf(z, h - nn, nn);                                                     \
} while (0)

// 1024 blocks x 256 threads (4 waves). Lane = (lab = tid>>2, f = tid&3).
// 4096 waves total = 4 waves/SIMD -> TLP hides trans latency & dep chains.
// No LDS / no barriers in the main loop: h exchange via DPP, x via prefetched
// global_load_dwordx4.
__global__ __launch_bounds__(256, 4)
void mcgru_quad(const float* __restrict__ x,
                const float* __restrict__ stat,
                const float* __restrict__ demo_W,
                const float* __restrict__ demo_b,
                const float* __restrict__ lab_W,
                const float* __restrict__ lab_b,
                const float* __restrict__ Wih,
                const float* __restrict__ bih,
                const float* __restrict__ Whh,
                const float* __restrict__ bhh,
                const float* __restrict__ out_W,
                const float* __restrict__ out_b,
                float* __restrict__ out)
{
    const int tid = threadIdx.x;
    const int b   = blockIdx.x;
    const int l   = tid >> 2;       // lab 0..63
    const int f   = tid & 3;        // hidden element 0..3

    __shared__ float cat[HID + LAB * FF];   // 288 floats

    const float S1 = -1.442695041f;   // -log2(e): r,z gates
    const float S2 =  2.885390082f;   // 2*log2(e): n gate

    // ---- per-lane weights (all small; stay register-resident) ----
    const float4* wlp = reinterpret_cast<const float4*>(lab_W + l * LAB + f * 16);
    const float4 wl0 = wlp[0], wl1 = wlp[1], wl2 = wlp[2], wl3 = wlp[3];

    float4 whr = *reinterpret_cast<const float4*>(Whh + l * 48 + f * 4);
    float4 whz = *reinterpret_cast<const float4*>(Whh + l * 48 + (4 + f) * 4);
    float4 whn = *reinterpret_cast<const float4*>(Whh + l * 48 + (8 + f) * 4);
    whr.x *= S1; whr.y *= S1; whr.z *= S1; whr.w *= S1;
    whz.x *= S1; whz.y *= S1; whz.z *= S1; whz.w *= S1;
    whn.x *= S2; whn.y *= S2; whn.z *= S2; whn.w *= S2;

    const float wir = Wih[l * 12 + f]     * S1;
    const float wiz = Wih[l * 12 + 4 + f] * S1;
    const float win = Wih[l * 12 + 8 + f] * S2;
    const float bcr = S1 * (bih[l * 12 + f]     + bhh[l * 12 + f]);
    const float bcz = S1 * (bih[l * 12 + 4 + f] + bhh[l * 12 + 4 + f]);
    const float bin = S2 *  bih[l * 12 + 8 + f];
    const float bhn = S2 *  bhh[l * 12 + 8 + f];
    const float lb  = lab_b[l];

    float h = 0.f;

    // x row t: 64 floats; this lane's slice = float4s [f*4 .. f*4+3]
    const float4* xrow = reinterpret_cast<const float4*>(x + (size_t)b * TT * LAB);
    const int base = f * 4;

    // prologue: t=0 slice
    float4 xa0 = xrow[base], xa1 = xrow[base + 1], xa2 = xrow[base + 2], xa3 = xrow[base + 3];

    #pragma unroll 1
    for (int tb = 0; tb < TT / 2; ++tb) {
        const int t1 = 2 * tb + 1;
        const int o1 = t1 * 16 + base;
        float4 xb0 = xrow[o1], xb1 = xrow[o1 + 1], xb2 = xrow[o1 + 2], xb3 = xrow[o1 + 3];

        GRU_STEP(xa0, xa1, xa2, xa3);          // t = 2*tb

        const int t2 = (t1 + 1 < TT) ? (t1 + 1) : (TT - 1);   // clamp avoids OOB tail load
        const int o2 = t2 * 16 + base;
        xa0 = xrow[o2]; xa1 = xrow[o2 + 1]; xa2 = xrow[o2 + 2]; xa3 = xrow[o2 + 3];

        GRU_STEP(xb0, xb1, xb2, xb3);          // t = 2*tb+1
    }

    // ---- epilogue: feat[l*4+f] == cat[HID + tid] ----
    cat[HID + tid] = h;
    if (tid < HID) {
        float acc = demo_b[tid];
        const float* sr  = stat + (size_t)b * DEMO;
        const float* dwr = demo_W + tid * DEMO;
        #pragma unroll
        for (int d = 0; d < DEMO; ++d)
            acc = fmaf(sr[d], dwr[d], acc);
        cat[tid] = acc;
    }
    __syncthreads();

    if (tid < HID) {
        float acc = out_b[tid];
        const float* wrow = out_W + tid * (HID + LAB * FF);
        #pragma unroll
        for (int i = 0; i < HID + LAB * FF; i += 4) {
            float4 wv = *reinterpret_cast<const float4*>(wrow + i);
            acc = fmaf(cat[i + 0], wv.x, acc);
            acc = fmaf(cat[i + 1], wv.y, acc);
            acc = fmaf(cat[i + 2], wv.z, acc);
            acc = fmaf(cat[i + 3], wv.w, acc);
        }
        out[(size_t)b * HID + tid] = acc;
    }
}

extern "C" void kernel_launch(void* const* d_in, const int* in_sizes, int n_in,
                              void* d_out, int out_size, void* d_ws, size_t ws_size,
                              hipStream_t stream) {
    const float* x      = (const float*)d_in[0];
    const float* stat   = (const float*)d_in[1];
    const float* demo_W = (const float*)d_in[2];
    const float* demo_b = (const float*)d_in[3];
    const float* lab_W  = (const float*)d_in[4];
    const float* lab_b  = (const float*)d_in[5];
    const float* Wih    = (const float*)d_in[6];
    const float* bih    = (const float*)d_in[7];
    const float* Whh    = (const float*)d_in[8];
    const float* bhh    = (const float*)d_in[9];
    const float* out_W  = (const float*)d_in[10];
    const float* out_b  = (const float*)d_in[11];
    float* out = (float*)d_out;

    hipLaunchKernelGGL(mcgru_quad, dim3(BSZ), dim3(256), 0, stream,
                       x, stat, demo_W, demo_b, lab_W, lab_b,
                       Wih, bih, Whh, bhh, out_W, out_b, out);
}